// Round 6
// baseline (502.858 us; speedup 1.0000x reference)
//
#include <hip/hip_runtime.h>

// ---------------------------------------------------------------------------
// ChebConv (K=4) x3 + relu + log_softmax.
// Plane-major bf16 features [4][N][32cols]; XCD-affine column-split ELL props;
// bf16-MFMA fused GEMM (K=512); log_softmax fused into the last GEMM.
// ---------------------------------------------------------------------------

typedef __attribute__((ext_vector_type(4))) float f32x4;
typedef __attribute__((ext_vector_type(8))) short bf16x8;

#define ELL_CAP 64

static __device__ __forceinline__ unsigned short f2bf(float f) {
    unsigned int u = __float_as_uint(f);
    u = (u + 0x7fff + ((u >> 16) & 1)) >> 16;   // RNE
    return (unsigned short)u;
}
static __device__ __forceinline__ float bflo(unsigned int p) {
    return __uint_as_float(p << 16);
}
static __device__ __forceinline__ float bfhi(unsigned int p) {
    return __uint_as_float(p & 0xffff0000u);
}

// ---------------- build ----------------

// one pass: weighted degree by src + ELL append {src, w}
__global__ __launch_bounds__(256) void scatter_kernel(
    const int* __restrict__ src, const int* __restrict__ dst,
    const float* __restrict__ w, float* __restrict__ deg,
    int* __restrict__ cnt, int2* __restrict__ ell, int E)
{
    int e = blockIdx.x * 256 + threadIdx.x;
    if (e >= E) return;
    int s = src[e], d = dst[e];
    float ww = w[e];
    float wd = (s == d) ? 0.f : ww;
    if (wd != 0.f) atomicAdd(&deg[s], wd);
    int pos = atomicAdd(&cnt[d], 1);
    if (pos < ELL_CAP)
        ell[(size_t)d * ELL_CAP + pos] = make_int2(s, __float_as_int(ww));
}

// dis = deg>0 ? rsqrt(deg) : 0   (in place)
__global__ __launch_bounds__(256) void dis_kernel(float* __restrict__ deg, int N)
{
    int n = blockIdx.x * 256 + threadIdx.x;
    if (n >= N) return;
    float d = deg[n];
    deg[n] = d > 0.f ? rsqrtf(d) : 0.f;
}

// wave per node: w -> norm = -dis[s]*w*dis[node]; self-loop->0; pad row to 8
__global__ __launch_bounds__(256) void normpad_kernel(
    const float* __restrict__ dis, int* __restrict__ cnt,
    int2* __restrict__ ell, int N)
{
    int node = blockIdx.x * 4 + (threadIdx.x >> 6);
    if (node >= N) return;
    int lane = threadIdx.x & 63;
    int c = cnt[node];
    if (c > ELL_CAP) c = ELL_CAP;
    int c8 = (c + 7) & ~7;
    int2* row = ell + (size_t)node * ELL_CAP;
    if (lane < c8) {
        int2 ent = (lane < c) ? row[lane] : make_int2(0, 0);
        float nm = 0.f;
        if (lane < c && ent.x != node)
            nm = -dis[ent.x] * __int_as_float(ent.y) * dis[node];
        row[lane] = make_int2((lane < c) ? ent.x : 0, __float_as_int(nm));
    }
    if (lane == 0) cnt[node] = c8;
}

// ---------------- conversions ----------------

// f32 [N][128] -> plane-major packed bf16 pairs: out[g][n][16 uints], g=col/32
__global__ __launch_bounds__(256) void cvt_x_kernel(
    const float* __restrict__ in, unsigned int* __restrict__ out, int N)
{
    long long i = (long long)blockIdx.x * 256 + threadIdx.x;
    if (i >= (long long)N * 64) return;
    int n = (int)(i >> 6);
    int u = (int)(i & 63);
    float2 v = *reinterpret_cast<const float2*>(&in[i * 2]);
    unsigned int pk = (unsigned int)f2bf(v.x) | ((unsigned int)f2bf(v.y) << 16);
    out[((size_t)(u >> 4) * N + n) * 16 + (u & 15)] = pk;
}

// W (4,128,BN) f32 -> Wt [BN][512] bf16  (Wt[n][kk*128+k] = W[kk][k][n])
__global__ __launch_bounds__(256) void cvt_w_kernel(
    const float* __restrict__ W, unsigned short* __restrict__ Wt, int BN)
{
    int idx = blockIdx.x * 256 + threadIdx.x;
    if (idx >= BN * 512) return;
    int n = idx >> 9;
    int kg = idx & 511;
    int kk = kg >> 7, k = kg & 127;
    Wt[(size_t)n * 512 + kg] = f2bf(W[((size_t)kk * 128 + k) * BN + n]);
}

// ---------------- prop: column-split, XCD-affine ----------------
// Feature planes [4][N][16 uints].  Block: 16 nodes x 16 lanes; colgroup from
// blockIdx&7 so (with round-robin XCD dispatch) each XCD pair only touches one
// 3.2MB plane -> L2-resident gathers.
template<bool FUSE>
__global__ __launch_bounds__(256) void prop_ell_cs(
    const unsigned int* __restrict__ v,
    const int* __restrict__ cnt,            // rounded-to-8 row lengths
    const int2* __restrict__ ell,           // [N][ELL_CAP] {src, norm bits}
    const unsigned int* __restrict__ prev,
    unsigned int* __restrict__ out, int N, int nodeBlocks)
{
    int b = blockIdx.x;
    int g = (b & 7) >> 1;
    int nodeblk = ((b >> 3) << 1) | (b & 1);
    if (nodeblk >= nodeBlocks) return;
    int tid = threadIdx.x;
    int node = nodeblk * 16 + (tid >> 4);
    if (node >= N) return;
    int li = tid & 15;
    const unsigned int* vp = v + (size_t)g * N * 16;
    int n8 = cnt[node];
    const int2* row = ell + (size_t)node * ELL_CAP;

    float ax[8], ay[8];
#pragma unroll
    for (int i = 0; i < 8; ++i) { ax[i] = 0.f; ay[i] = 0.f; }

    for (int e = 0; e < n8; e += 8) {
        int4 q0 = *reinterpret_cast<const int4*>(row + e);
        int4 q1 = *reinterpret_cast<const int4*>(row + e + 2);
        int4 q2 = *reinterpret_cast<const int4*>(row + e + 4);
        int4 q3 = *reinterpret_cast<const int4*>(row + e + 6);
        unsigned int p0 = vp[(size_t)q0.x * 16 + li];
        unsigned int p1 = vp[(size_t)q0.z * 16 + li];
        unsigned int p2 = vp[(size_t)q1.x * 16 + li];
        unsigned int p3 = vp[(size_t)q1.z * 16 + li];
        unsigned int p4 = vp[(size_t)q2.x * 16 + li];
        unsigned int p5 = vp[(size_t)q2.z * 16 + li];
        unsigned int p6 = vp[(size_t)q3.x * 16 + li];
        unsigned int p7 = vp[(size_t)q3.z * 16 + li];
        float n0 = __int_as_float(q0.y), n1 = __int_as_float(q0.w);
        float n2 = __int_as_float(q1.y), n3 = __int_as_float(q1.w);
        float n4 = __int_as_float(q2.y), n5 = __int_as_float(q2.w);
        float n6 = __int_as_float(q3.y), n7 = __int_as_float(q3.w);
        ax[0] = fmaf(n0, bflo(p0), ax[0]); ay[0] = fmaf(n0, bfhi(p0), ay[0]);
        ax[1] = fmaf(n1, bflo(p1), ax[1]); ay[1] = fmaf(n1, bfhi(p1), ay[1]);
        ax[2] = fmaf(n2, bflo(p2), ax[2]); ay[2] = fmaf(n2, bfhi(p2), ay[2]);
        ax[3] = fmaf(n3, bflo(p3), ax[3]); ay[3] = fmaf(n3, bfhi(p3), ay[3]);
        ax[4] = fmaf(n4, bflo(p4), ax[4]); ay[4] = fmaf(n4, bfhi(p4), ay[4]);
        ax[5] = fmaf(n5, bflo(p5), ax[5]); ay[5] = fmaf(n5, bfhi(p5), ay[5]);
        ax[6] = fmaf(n6, bflo(p6), ax[6]); ay[6] = fmaf(n6, bfhi(p6), ay[6]);
        ax[7] = fmaf(n7, bflo(p7), ax[7]); ay[7] = fmaf(n7, bfhi(p7), ay[7]);
    }
    float ox = ((ax[0] + ax[1]) + (ax[2] + ax[3])) + ((ax[4] + ax[5]) + (ax[6] + ax[7]));
    float oy = ((ay[0] + ay[1]) + (ay[2] + ay[3])) + ((ay[4] + ay[5]) + (ay[6] + ay[7]));
    size_t oidx = ((size_t)g * N + node) * 16 + li;
    if (FUSE) {
        unsigned int pp = prev[oidx];
        ox = 2.f * ox - bflo(pp);
        oy = 2.f * oy - bfhi(pp);
    }
    out[oidx] = (unsigned int)f2bf(ox) | ((unsigned int)f2bf(oy) << 16);
}

// ---------------- fused Chebyshev GEMM (bf16 MFMA) ----------------
// T buffers are plane-major [4][N][32 shorts].  out = relu(sum_k T_k@W_k + b).
// LAST: log_softmax fused via LDS staging.
template<int BN, bool LAST>
__global__ __launch_bounds__(256) void cheb_gemm_bf(
    const unsigned short* __restrict__ T0, const unsigned short* __restrict__ T1,
    const unsigned short* __restrict__ T2, const unsigned short* __restrict__ T3,
    const unsigned short* __restrict__ Wt,  // [BN][512] bf16
    const float* __restrict__ bias,
    unsigned short* __restrict__ out_bf,    // plane-major [4][N][32] (if !LAST)
    float* __restrict__ out_f,              // [N][64] f32 (if LAST)
    int nNodes)
{
    constexpr int BM = 64, BK = 64;
    constexpr int CT = BN / 64;             // 16-col tiles per wave: 2 or 1
    constexpr size_t SMA = (size_t)BM * BK * 2;
    constexpr size_t SMB = (size_t)BN * BK * 2;
    constexpr size_t SML = LAST ? (size_t)BM * 64 * 4 : 0;
    constexpr size_t SMEM = (SMA + SMB) > SML ? (SMA + SMB) : SML;
    __shared__ __align__(16) char smem[SMEM];
    unsigned short* As = (unsigned short*)smem;
    unsigned short* Bs = As + BM * BK;

    const int tid  = threadIdx.x;
    const int wave = tid >> 6;
    const int lane = tid & 63;
    const int row0 = blockIdx.x * BM;

    f32x4 acc[4][CT];
#pragma unroll
    for (int i = 0; i < 4; i++)
#pragma unroll
        for (int j = 0; j < CT; j++) acc[i][j] = (f32x4)0.f;

    const unsigned short* Ts[4] = {T0, T1, T2, T3};
    const int lk = lane >> 4;
    const int lr = lane & 15;

#pragma unroll 1
    for (int k0 = 0; k0 < 512; k0 += BK) {
        const unsigned short* T = Ts[k0 >> 7];
        const int kin = k0 & 127;
#pragma unroll
        for (int it = 0; it < 2; ++it) {
            int c  = tid + it * 256;
            int r  = c >> 3, cc = c & 7;
            int gr = row0 + r;
            int col = kin + cc * 8;           // col in [0,128)
            uint4 val = make_uint4(0, 0, 0, 0);
            if (gr < nNodes)
                val = *reinterpret_cast<const uint4*>(
                    &T[((size_t)(col >> 5) * nNodes + gr) * 32 + (col & 31)]);
            *reinterpret_cast<uint4*>(&As[r * 64 + (cc ^ (r & 7)) * 8]) = val;
        }
#pragma unroll
        for (int c = tid; c < BN * 8; c += 256) {
            int n = c >> 3, cc = c & 7;
            uint4 val = *reinterpret_cast<const uint4*>(&Wt[(size_t)n * 512 + k0 + cc * 8]);
            *reinterpret_cast<uint4*>(&Bs[n * 64 + (cc ^ (n & 7)) * 8]) = val;
        }
        __syncthreads();
#pragma unroll
        for (int ks = 0; ks < 2; ++ks) {
            bf16x8 afrag[4], bfrag[CT];
            int cb = ks * 4 + lk;
#pragma unroll
            for (int i = 0; i < 4; ++i) {
                int r = i * 16 + lr;
                afrag[i] = *reinterpret_cast<const bf16x8*>(
                    &As[r * 64 + (cb ^ (r & 7)) * 8]);
            }
#pragma unroll
            for (int j = 0; j < CT; ++j) {
                int n = (wave * CT + j) * 16 + lr;
                bfrag[j] = *reinterpret_cast<const bf16x8*>(
                    &Bs[n * 64 + (cb ^ (n & 7)) * 8]);
            }
#pragma unroll
            for (int i = 0; i < 4; ++i)
#pragma unroll
                for (int j = 0; j < CT; ++j)
                    acc[i][j] = __builtin_amdgcn_mfma_f32_16x16x32_bf16(
                        afrag[i], bfrag[j], acc[i][j], 0, 0, 0);
        }
        __syncthreads();
    }

    if (!LAST) {
#pragma unroll
        for (int i = 0; i < 4; ++i) {
#pragma unroll
            for (int r = 0; r < 4; ++r) {
                int grow = row0 + i * 16 + (lane >> 4) * 4 + r;
                if (grow >= nNodes) continue;
#pragma unroll
                for (int j = 0; j < CT; ++j) {
                    int col = (wave * CT + j) * 16 + (lane & 15);
                    float val = acc[i][j][r] + bias[col];
                    out_bf[((size_t)(col >> 5) * nNodes + grow) * 32 + (col & 31)] =
                        f2bf(fmaxf(val, 0.f));
                }
            }
        }
    } else {
        float* lsm = (float*)smem;   // [64][64], As/Bs dead after last sync
#pragma unroll
        for (int i = 0; i < 4; ++i) {
#pragma unroll
            for (int r = 0; r < 4; ++r) {
                int lrow = i * 16 + (lane >> 4) * 4 + r;
                int col = wave * 16 + (lane & 15);
                lsm[lrow * 64 + col] = fmaxf(acc[i][0][r] + bias[col], 0.f);
            }
        }
        __syncthreads();
#pragma unroll 1
        for (int r = 0; r < 16; ++r) {
            int lrow = wave * 16 + r;
            int grow = row0 + lrow;
            if (grow >= nNodes) continue;
            float vv = lsm[lrow * 64 + lane];
            float m = vv;
#pragma unroll
            for (int o = 32; o > 0; o >>= 1) m = fmaxf(m, __shfl_xor(m, o));
            float ee = expf(vv - m);
            float s = ee;
#pragma unroll
            for (int o = 32; o > 0; o >>= 1) s += __shfl_xor(s, o);
            out_f[(size_t)grow * 64 + lane] = vv - m - logf(s);
        }
    }
}

// ---------------- launch ----------------

extern "C" void kernel_launch(void* const* d_in, const int* in_sizes, int n_in,
                              void* d_out, int out_size, void* d_ws, size_t ws_size,
                              hipStream_t stream)
{
    const float* x     = (const float*)d_in[0];
    const int*   ei    = (const int*)d_in[1];
    const float* eattr = (const float*)d_in[2];
    const float* Ws1   = (const float*)d_in[3];
    const float* b1    = (const float*)d_in[4];
    const float* Ws2   = (const float*)d_in[5];
    const float* b2    = (const float*)d_in[6];
    const float* Ws3   = (const float*)d_in[7];
    const float* b3    = (const float*)d_in[8];

    const int N = in_sizes[0] / 128;
    const int E = in_sizes[2];
    const int* src = ei;
    const int* dst = ei + E;

    char* ws = (char*)d_ws;
    size_t off = 0;
    auto alloc = [&](size_t bytes) {
        void* p = ws + off;
        off = (off + bytes + 255) & ~(size_t)255;
        return p;
    };
    float* deg = (float*)alloc((size_t)N * 4);        // becomes dis in place
    int*   cnt = (int*)  alloc((size_t)N * 4);
    int2*  ell = (int2*) alloc((size_t)N * ELL_CAP * 8);
    unsigned int* xb = (unsigned int*)alloc((size_t)N * 64 * 4);
    unsigned int* A  = (unsigned int*)alloc((size_t)N * 64 * 4);
    unsigned int* B  = (unsigned int*)alloc((size_t)N * 64 * 4);
    unsigned int* C  = (unsigned int*)alloc((size_t)N * 64 * 4);
    unsigned int* Db = (unsigned int*)alloc((size_t)N * 64 * 4);
    unsigned int* Eb = (unsigned int*)alloc((size_t)N * 64 * 4);
    unsigned short* W1t = (unsigned short*)alloc((size_t)128 * 512 * 2);
    unsigned short* W2t = (unsigned short*)alloc((size_t)128 * 512 * 2);
    unsigned short* W3t = (unsigned short*)alloc((size_t)64  * 512 * 2);

    const int eb  = (E + 255) / 256;
    const int gb  = (N + 63) / 64;
    const int nodeBlocks = (N + 15) / 16;
    const int pgrid = ((nodeBlocks + 1) / 2) * 8;

    // ---- conversions + ELL build ----
    cvt_x_kernel<<<(int)(((long long)N * 64 + 255) / 256), 256, 0, stream>>>(x, xb, N);
    cvt_w_kernel<<<(128 * 512 + 255) / 256, 256, 0, stream>>>(Ws1, W1t, 128);
    cvt_w_kernel<<<(128 * 512 + 255) / 256, 256, 0, stream>>>(Ws2, W2t, 128);
    cvt_w_kernel<<<(64 * 512 + 255) / 256, 256, 0, stream>>>(Ws3, W3t, 64);

    hipMemsetAsync(deg, 0, (size_t)N * 4, stream);
    hipMemsetAsync(cnt, 0, (size_t)N * 4, stream);
    scatter_kernel<<<eb, 256, 0, stream>>>(src, dst, eattr, deg, cnt, ell, E);
    dis_kernel<<<(N + 255) / 256, 256, 0, stream>>>(deg, N);
    normpad_kernel<<<(N + 3) / 4, 256, 0, stream>>>(deg, cnt, ell, N);

    auto ush = [](unsigned int* p) { return (unsigned short*)p; };

    // ---- layer 1: T0 = xb ----
    prop_ell_cs<false><<<pgrid, 256, 0, stream>>>(xb, cnt, ell, nullptr, A, N, nodeBlocks);
    prop_ell_cs<true ><<<pgrid, 256, 0, stream>>>(A, cnt, ell, xb, B, N, nodeBlocks);
    prop_ell_cs<true ><<<pgrid, 256, 0, stream>>>(B, cnt, ell, A, C, N, nodeBlocks);
    cheb_gemm_bf<128, false><<<gb, 256, 0, stream>>>(
        ush(xb), ush(A), ush(B), ush(C), W1t, b1, ush(Db), nullptr, N);

    // ---- layer 2: T0 = Db ----
    prop_ell_cs<false><<<pgrid, 256, 0, stream>>>(Db, cnt, ell, nullptr, A, N, nodeBlocks);
    prop_ell_cs<true ><<<pgrid, 256, 0, stream>>>(A, cnt, ell, Db, B, N, nodeBlocks);
    prop_ell_cs<true ><<<pgrid, 256, 0, stream>>>(B, cnt, ell, A, C, N, nodeBlocks);
    cheb_gemm_bf<128, false><<<gb, 256, 0, stream>>>(
        ush(Db), ush(A), ush(B), ush(C), W2t, b2, ush(Eb), nullptr, N);

    // ---- layer 3: T0 = Eb, logits+log_softmax -> d_out ----
    prop_ell_cs<false><<<pgrid, 256, 0, stream>>>(Eb, cnt, ell, nullptr, A, N, nodeBlocks);
    prop_ell_cs<true ><<<pgrid, 256, 0, stream>>>(A, cnt, ell, Eb, B, N, nodeBlocks);
    prop_ell_cs<true ><<<pgrid, 256, 0, stream>>>(B, cnt, ell, A, C, N, nodeBlocks);
    cheb_gemm_bf<64, true><<<gb, 256, 0, stream>>>(
        ush(Eb), ush(A), ush(B), ush(C), W3t, b3, nullptr, (float*)d_out, N);
}

// Round 7
// 453.807 us; speedup vs baseline: 1.1081x; 1.1081x over previous
//
#include <hip/hip_runtime.h>

// ---------------------------------------------------------------------------
// ChebConv (K=4) x3 + relu + log_softmax.
// Row-major bf16 features [N][64 uints]; 4B-packed ELL {u16 src, f16 norm};
// 32-deep gather batches in prop; bf16-MFMA fused GEMM (K=512);
// log_softmax fused into the last GEMM.
// ---------------------------------------------------------------------------

typedef __attribute__((ext_vector_type(4))) float f32x4;
typedef __attribute__((ext_vector_type(8))) short bf16x8;

#define ELL_CAP 64

static __device__ __forceinline__ unsigned short f2bf(float f) {
    unsigned int u = __float_as_uint(f);
    u = (u + 0x7fff + ((u >> 16) & 1)) >> 16;   // RNE
    return (unsigned short)u;
}
static __device__ __forceinline__ float bflo(unsigned int p) {
    return __uint_as_float(p << 16);
}
static __device__ __forceinline__ float bfhi(unsigned int p) {
    return __uint_as_float(p & 0xffff0000u);
}
static __device__ __forceinline__ unsigned short f2h(float f) {
    _Float16 h = (_Float16)f;
    return __builtin_bit_cast(unsigned short, h);
}
static __device__ __forceinline__ float h2f(unsigned short b) {
    return (float)__builtin_bit_cast(_Float16, b);
}

// ---------------- build ----------------

// one pass: weighted degree by src + ELL append {u16 src, f16 w}
__global__ __launch_bounds__(256) void scatter_kernel(
    const int* __restrict__ src, const int* __restrict__ dst,
    const float* __restrict__ w, float* __restrict__ deg,
    int* __restrict__ cnt, unsigned int* __restrict__ ell, int E)
{
    int e = blockIdx.x * 256 + threadIdx.x;
    if (e >= E) return;
    int s = src[e], d = dst[e];
    float ww = w[e];
    float wd = (s == d) ? 0.f : ww;
    if (wd != 0.f) atomicAdd(&deg[s], wd);
    int pos = atomicAdd(&cnt[d], 1);
    if (pos < ELL_CAP)
        ell[(size_t)d * ELL_CAP + pos] =
            (unsigned int)s | ((unsigned int)f2h(ww) << 16);
}

// dis = deg>0 ? rsqrt(deg) : 0   (in place)
__global__ __launch_bounds__(256) void dis_kernel(float* __restrict__ deg, int N)
{
    int n = blockIdx.x * 256 + threadIdx.x;
    if (n >= N) return;
    float d = deg[n];
    deg[n] = d > 0.f ? rsqrtf(d) : 0.f;
}

// wave per node: w -> norm = -dis[s]*w*dis[node]; self-loop->0; pad row to 8
__global__ __launch_bounds__(256) void normpad_kernel(
    const float* __restrict__ dis, int* __restrict__ cnt,
    unsigned int* __restrict__ ell, int N)
{
    int node = blockIdx.x * 4 + (threadIdx.x >> 6);
    if (node >= N) return;
    int lane = threadIdx.x & 63;
    int c = cnt[node];
    if (c > ELL_CAP) c = ELL_CAP;
    int c8 = (c + 7) & ~7;
    unsigned int* row = ell + (size_t)node * ELL_CAP;
    if (lane < c8) {
        unsigned int ent = (lane < c) ? row[lane] : 0u;
        int s = (int)(ent & 0xFFFFu);
        float nm = 0.f;
        if (lane < c && s != node)
            nm = -dis[s] * h2f((unsigned short)(ent >> 16)) * dis[node];
        row[lane] = (lane < c ? (unsigned int)s : 0u)
                  | ((unsigned int)f2h(nm) << 16);
    }
    if (lane == 0) cnt[node] = c8;
}

// ---------------- conversions ----------------

// f32 (N*128) -> packed bf16 pairs (N*64 uints), row-major
__global__ __launch_bounds__(256) void cvt_x_kernel(
    const float* __restrict__ in, unsigned int* __restrict__ out, long long n2)
{
    long long i = (long long)blockIdx.x * 256 + threadIdx.x;
    if (i >= n2) return;
    float2 v = *reinterpret_cast<const float2*>(&in[i * 2]);
    out[i] = (unsigned int)f2bf(v.x) | ((unsigned int)f2bf(v.y) << 16);
}

// W (4,128,BN) f32 -> Wt [BN][512] bf16  (Wt[n][kk*128+k] = W[kk][k][n])
__global__ __launch_bounds__(256) void cvt_w_kernel(
    const float* __restrict__ W, unsigned short* __restrict__ Wt, int BN)
{
    int idx = blockIdx.x * 256 + threadIdx.x;
    if (idx >= BN * 512) return;
    int n = idx >> 9;
    int kg = idx & 511;
    int kk = kg >> 7, k = kg & 127;
    Wt[(size_t)n * 512 + kg] = f2bf(W[((size_t)kk * 128 + k) * BN + n]);
}

// ---------------- prop (bf16 in/out, f32 accumulate) ----------------
// NB edges per batch: load all indices, issue all gathers, then FMA.
template<int NB>
static __device__ __forceinline__ void gather_batch(
    const unsigned int* __restrict__ row, int e,
    const unsigned int* __restrict__ v, int lane,
    float ax[8], float ay[8])
{
    uint4 q[NB / 4];
#pragma unroll
    for (int i = 0; i < NB / 4; ++i)
        q[i] = *reinterpret_cast<const uint4*>(row + e + i * 4);
    unsigned int ent[NB];
#pragma unroll
    for (int i = 0; i < NB / 4; ++i) {
        ent[i * 4 + 0] = q[i].x; ent[i * 4 + 1] = q[i].y;
        ent[i * 4 + 2] = q[i].z; ent[i * 4 + 3] = q[i].w;
    }
    unsigned int p[NB];
#pragma unroll
    for (int i = 0; i < NB; ++i)
        p[i] = v[(size_t)(ent[i] & 0xFFFFu) * 64 + lane];
#pragma unroll
    for (int i = 0; i < NB; ++i) {
        float nm = h2f((unsigned short)(ent[i] >> 16));
        ax[i & 7] = fmaf(nm, bflo(p[i]), ax[i & 7]);
        ay[i & 7] = fmaf(nm, bfhi(p[i]), ay[i & 7]);
    }
}

template<bool FUSE>
__global__ __launch_bounds__(256) void prop_ell_bf(
    const unsigned int* __restrict__ v,     // [N][64] packed bf16x2
    const int* __restrict__ cnt,            // rounded-to-8 row lengths
    const unsigned int* __restrict__ ell,   // [N][ELL_CAP] {u16 src, f16 norm}
    const unsigned int* __restrict__ prev,  // [N][64]
    unsigned int* __restrict__ out, int N)
{
    int node = blockIdx.x * 4 + (threadIdx.x >> 6);
    if (node >= N) return;
    int lane = threadIdx.x & 63;
    int n8 = cnt[node];
    const unsigned int* row = ell + (size_t)node * ELL_CAP;

    float ax[8], ay[8];
#pragma unroll
    for (int i = 0; i < 8; ++i) { ax[i] = 0.f; ay[i] = 0.f; }

    int e = 0;
    while (e < n8) {
        int rem = n8 - e;
        if (rem >= 32)      { gather_batch<32>(row, e, v, lane, ax, ay); e += 32; }
        else if (rem >= 16) { gather_batch<16>(row, e, v, lane, ax, ay); e += 16; }
        else                { gather_batch<8> (row, e, v, lane, ax, ay); e += 8;  }
    }

    float ox = ((ax[0] + ax[1]) + (ax[2] + ax[3])) + ((ax[4] + ax[5]) + (ax[6] + ax[7]));
    float oy = ((ay[0] + ay[1]) + (ay[2] + ay[3])) + ((ay[4] + ay[5]) + (ay[6] + ay[7]));
    if (FUSE) {
        unsigned int pp = prev[(size_t)node * 64 + lane];
        ox = 2.f * ox - bflo(pp);
        oy = 2.f * oy - bfhi(pp);
    }
    out[(size_t)node * 64 + lane] =
        (unsigned int)f2bf(ox) | ((unsigned int)f2bf(oy) << 16);
}

// ---------------- fused Chebyshev GEMM (bf16 MFMA) ----------------
// out[n][:] = relu( [T0|T1|T2|T3](n,:) @ Wt^T + bias ),  K = 512.
// LAST: log_softmax fused via LDS staging (block owns 64 rows x 64 cols).
template<int BN, bool LAST>
__global__ __launch_bounds__(256) void cheb_gemm_bf(
    const unsigned short* __restrict__ T0, const unsigned short* __restrict__ T1,
    const unsigned short* __restrict__ T2, const unsigned short* __restrict__ T3,
    const unsigned short* __restrict__ Wt,  // [BN][512] bf16
    const float* __restrict__ bias,
    unsigned short* __restrict__ out_bf,    // [N][128] bf16 (if !LAST)
    float* __restrict__ out_f,              // [N][64] f32 (if LAST)
    int nNodes)
{
    constexpr int BM = 64, BK = 64;
    constexpr int CT = BN / 64;             // 16-col tiles per wave: 2 or 1
    constexpr size_t SMA = (size_t)BM * BK * 2;
    constexpr size_t SMB = (size_t)BN * BK * 2;
    constexpr size_t SML = LAST ? (size_t)BM * 64 * 4 : 0;
    constexpr size_t SMEM = (SMA + SMB) > SML ? (SMA + SMB) : SML;
    __shared__ __align__(16) char smem[SMEM];
    unsigned short* As = (unsigned short*)smem;
    unsigned short* Bs = As + BM * BK;

    const int tid  = threadIdx.x;
    const int wave = tid >> 6;
    const int lane = tid & 63;
    const int row0 = blockIdx.x * BM;

    f32x4 acc[4][CT];
#pragma unroll
    for (int i = 0; i < 4; i++)
#pragma unroll
        for (int j = 0; j < CT; j++) acc[i][j] = (f32x4)0.f;

    const unsigned short* Ts[4] = {T0, T1, T2, T3};
    const int lk = lane >> 4;
    const int lr = lane & 15;

#pragma unroll 1
    for (int k0 = 0; k0 < 512; k0 += BK) {
        const unsigned short* T = Ts[k0 >> 7];
        const int kin = k0 & 127;
#pragma unroll
        for (int it = 0; it < 2; ++it) {
            int c  = tid + it * 256;
            int r  = c >> 3, cc = c & 7;
            int gr = row0 + r;
            uint4 val = make_uint4(0, 0, 0, 0);
            if (gr < nNodes)
                val = *reinterpret_cast<const uint4*>(&T[(size_t)gr * 128 + kin + cc * 8]);
            *reinterpret_cast<uint4*>(&As[r * 64 + (cc ^ (r & 7)) * 8]) = val;
        }
#pragma unroll
        for (int c = tid; c < BN * 8; c += 256) {
            int n = c >> 3, cc = c & 7;
            uint4 val = *reinterpret_cast<const uint4*>(&Wt[(size_t)n * 512 + k0 + cc * 8]);
            *reinterpret_cast<uint4*>(&Bs[n * 64 + (cc ^ (n & 7)) * 8]) = val;
        }
        __syncthreads();
#pragma unroll
        for (int ks = 0; ks < 2; ++ks) {
            bf16x8 afrag[4], bfrag[CT];
            int cb = ks * 4 + lk;
#pragma unroll
            for (int i = 0; i < 4; ++i) {
                int r = i * 16 + lr;
                afrag[i] = *reinterpret_cast<const bf16x8*>(
                    &As[r * 64 + (cb ^ (r & 7)) * 8]);
            }
#pragma unroll
            for (int j = 0; j < CT; ++j) {
                int n = (wave * CT + j) * 16 + lr;
                bfrag[j] = *reinterpret_cast<const bf16x8*>(
                    &Bs[n * 64 + (cb ^ (n & 7)) * 8]);
            }
#pragma unroll
            for (int i = 0; i < 4; ++i)
#pragma unroll
                for (int j = 0; j < CT; ++j)
                    acc[i][j] = __builtin_amdgcn_mfma_f32_16x16x32_bf16(
                        afrag[i], bfrag[j], acc[i][j], 0, 0, 0);
        }
        __syncthreads();
    }

    if (!LAST) {
#pragma unroll
        for (int i = 0; i < 4; ++i) {
#pragma unroll
            for (int r = 0; r < 4; ++r) {
                int grow = row0 + i * 16 + (lane >> 4) * 4 + r;
                if (grow >= nNodes) continue;
#pragma unroll
                for (int j = 0; j < CT; ++j) {
                    int col = (wave * CT + j) * 16 + (lane & 15);
                    float val = acc[i][j][r] + bias[col];
                    out_bf[(size_t)grow * 128 + col] = f2bf(fmaxf(val, 0.f));
                }
            }
        }
    } else {
        float* lsm = (float*)smem;   // [64][64], As/Bs dead after last sync
#pragma unroll
        for (int i = 0; i < 4; ++i) {
#pragma unroll
            for (int r = 0; r < 4; ++r) {
                int lrow = i * 16 + (lane >> 4) * 4 + r;
                int col = wave * 16 + (lane & 15);
                lsm[lrow * 64 + col] = fmaxf(acc[i][0][r] + bias[col], 0.f);
            }
        }
        __syncthreads();
#pragma unroll 1
        for (int r = 0; r < 16; ++r) {
            int lrow = wave * 16 + r;
            int grow = row0 + lrow;
            if (grow >= nNodes) continue;
            float vv = lsm[lrow * 64 + lane];
            float m = vv;
#pragma unroll
            for (int o = 32; o > 0; o >>= 1) m = fmaxf(m, __shfl_xor(m, o));
            float ee = expf(vv - m);
            float s = ee;
#pragma unroll
            for (int o = 32; o > 0; o >>= 1) s += __shfl_xor(s, o);
            out_f[(size_t)grow * 64 + lane] = vv - m - logf(s);
        }
    }
}

// ---------------- launch ----------------

extern "C" void kernel_launch(void* const* d_in, const int* in_sizes, int n_in,
                              void* d_out, int out_size, void* d_ws, size_t ws_size,
                              hipStream_t stream)
{
    const float* x     = (const float*)d_in[0];
    const int*   ei    = (const int*)d_in[1];
    const float* eattr = (const float*)d_in[2];
    const float* Ws1   = (const float*)d_in[3];
    const float* b1    = (const float*)d_in[4];
    const float* Ws2   = (const float*)d_in[5];
    const float* b2    = (const float*)d_in[6];
    const float* Ws3   = (const float*)d_in[7];
    const float* b3    = (const float*)d_in[8];

    const int N = in_sizes[0] / 128;
    const int E = in_sizes[2];
    const int* src = ei;
    const int* dst = ei + E;

    char* ws = (char*)d_ws;
    size_t off = 0;
    auto alloc = [&](size_t bytes) {
        void* p = ws + off;
        off = (off + bytes + 255) & ~(size_t)255;
        return p;
    };
    float* deg = (float*)alloc((size_t)N * 4);        // becomes dis in place
    int*   cnt = (int*)  alloc((size_t)N * 4);
    unsigned int* ell = (unsigned int*)alloc((size_t)N * ELL_CAP * 4);
    unsigned int* xb = (unsigned int*)alloc((size_t)N * 64 * 4);
    unsigned int* A  = (unsigned int*)alloc((size_t)N * 64 * 4);
    unsigned int* B  = (unsigned int*)alloc((size_t)N * 64 * 4);
    unsigned int* C  = (unsigned int*)alloc((size_t)N * 64 * 4);
    unsigned int* Db = (unsigned int*)alloc((size_t)N * 64 * 4);
    unsigned int* Eb = (unsigned int*)alloc((size_t)N * 64 * 4);
    unsigned short* W1t = (unsigned short*)alloc((size_t)128 * 512 * 2);
    unsigned short* W2t = (unsigned short*)alloc((size_t)128 * 512 * 2);
    unsigned short* W3t = (unsigned short*)alloc((size_t)64  * 512 * 2);

    const int eb  = (E + 255) / 256;
    const int pbl = (N + 3) / 4;
    const int gb  = (N + 63) / 64;
    const long long n2 = (long long)N * 64;

    // ---- conversions + ELL build ----
    cvt_x_kernel<<<(int)((n2 + 255) / 256), 256, 0, stream>>>(x, xb, n2);
    cvt_w_kernel<<<(128 * 512 + 255) / 256, 256, 0, stream>>>(Ws1, W1t, 128);
    cvt_w_kernel<<<(128 * 512 + 255) / 256, 256, 0, stream>>>(Ws2, W2t, 128);
    cvt_w_kernel<<<(64 * 512 + 255) / 256, 256, 0, stream>>>(Ws3, W3t, 64);

    hipMemsetAsync(deg, 0, (size_t)N * 4, stream);
    hipMemsetAsync(cnt, 0, (size_t)N * 4, stream);
    scatter_kernel<<<eb, 256, 0, stream>>>(src, dst, eattr, deg, cnt, ell, E);
    dis_kernel<<<(N + 255) / 256, 256, 0, stream>>>(deg, N);
    normpad_kernel<<<(N + 3) / 4, 256, 0, stream>>>(deg, cnt, ell, N);

    auto ush = [](unsigned int* p) { return (unsigned short*)p; };

    // ---- layer 1: T0 = xb ----
    prop_ell_bf<false><<<pbl, 256, 0, stream>>>(xb, cnt, ell, nullptr, A, N);
    prop_ell_bf<true ><<<pbl, 256, 0, stream>>>(A, cnt, ell, xb, B, N);
    prop_ell_bf<true ><<<pbl, 256, 0, stream>>>(B, cnt, ell, A, C, N);
    cheb_gemm_bf<128, false><<<gb, 256, 0, stream>>>(
        ush(xb), ush(A), ush(B), ush(C), W1t, b1, ush(Db), nullptr, N);

    // ---- layer 2: T0 = Db ----
    prop_ell_bf<false><<<pbl, 256, 0, stream>>>(Db, cnt, ell, nullptr, A, N);
    prop_ell_bf<true ><<<pbl, 256, 0, stream>>>(A, cnt, ell, Db, B, N);
    prop_ell_bf<true ><<<pbl, 256, 0, stream>>>(B, cnt, ell, A, C, N);
    cheb_gemm_bf<128, false><<<gb, 256, 0, stream>>>(
        ush(Db), ush(A), ush(B), ush(C), W2t, b2, ush(Eb), nullptr, N);

    // ---- layer 3: T0 = Eb, logits+log_softmax -> d_out ----
    prop_ell_bf<false><<<pbl, 256, 0, stream>>>(Eb, cnt, ell, nullptr, A, N);
    prop_ell_bf<true ><<<pbl, 256, 0, stream>>>(A, cnt, ell, Eb, B, N);
    prop_ell_bf<true ><<<pbl, 256, 0, stream>>>(B, cnt, ell, A, C, N);
    cheb_gemm_bf<64, true><<<gb, 256, 0, stream>>>(
        ush(Eb), ush(A), ush(B), ush(C), W3t, b3, nullptr, (float*)d_out, N);
}